// Round 9
// baseline (2223.104 us; speedup 1.0000x reference)
//
#include <hip/hip_runtime.h>
#include <hip/hip_bf16.h>
#include <hip/hip_fp16.h>

#define L_SEQ 16384
#define HDIM  1024
#define CH    32
#define NC    (L_SEQ / CH)   // 512 chunks

typedef _Float16 f16;
typedef _Float16 f16x8 __attribute__((ext_vector_type(8)));
typedef _Float16 f16x4 __attribute__((ext_vector_type(4)));
typedef float    f32x4 __attribute__((ext_vector_type(4)));

#define AS1(p) (const __attribute__((address_space(1))) void*)(p)
#define AS3(p) (__attribute__((address_space(3))) void*)(p)

// -------- weight convert + transpose: out[n*K+k] = (f16) in[k*N+n] --------
__global__ __launch_bounds__(256) void wcvt_t(const float* __restrict__ in,
                                              f16* __restrict__ out, int K, int N) {
  __shared__ float tile[32][33];
  int n0 = blockIdx.x * 32, k0 = blockIdx.y * 32;
  int tx = threadIdx.x, ty = threadIdx.y;  // (32,8)
#pragma unroll
  for (int i = 0; i < 4; i++) {
    int k = k0 + ty + i * 8;
    tile[ty + i * 8][tx] = in[(size_t)k * N + n0 + tx];
  }
  __syncthreads();
#pragma unroll
  for (int i = 0; i < 4; i++) {
    int n = n0 + ty + i * 8;
    out[(size_t)n * K + k0 + tx] = (f16)tile[tx][ty + i * 8];
  }
}

// -------- LayerNorm fp32 in -> f16 out (+ optional f16 copy of input) -----
__global__ __launch_bounds__(256) void ln_k(const float* __restrict__ x,
                                            const float* __restrict__ w,
                                            const float* __restrict__ b,
                                            f16* __restrict__ out,
                                            f16* __restrict__ xcopy) {
  int row = blockIdx.x;
  int t = threadIdx.x;
  const float4* xr = (const float4*)(x + (size_t)row * HDIM);
  float4 v = xr[t];
  float s  = v.x + v.y + v.z + v.w;
  float s2 = v.x * v.x + v.y * v.y + v.z * v.z + v.w * v.w;
#pragma unroll
  for (int off = 32; off > 0; off >>= 1) {
    s  += __shfl_down(s, off);
    s2 += __shfl_down(s2, off);
  }
  __shared__ float red[8];
  int wid = t >> 6, lane = t & 63;
  if (lane == 0) { red[wid] = s; red[4 + wid] = s2; }
  __syncthreads();
  if (t == 0) {
    red[0] = red[0] + red[1] + red[2] + red[3];
    red[4] = red[4] + red[5] + red[6] + red[7];
  }
  __syncthreads();
  float mean = red[0] * (1.0f / HDIM);
  float var  = red[4] * (1.0f / HDIM) - mean * mean;
  float rstd = rsqrtf(var + 1e-5f);
  float4 ww = ((const float4*)w)[t];
  float4 bb = ((const float4*)b)[t];
  f16x4 o;
  o[0] = (f16)((v.x - mean) * rstd * ww.x + bb.x);
  o[1] = (f16)((v.y - mean) * rstd * ww.y + bb.y);
  o[2] = (f16)((v.z - mean) * rstd * ww.z + bb.z);
  o[3] = (f16)((v.w - mean) * rstd * ww.w + bb.w);
  ((f16x4*)(out + (size_t)row * HDIM))[t] = o;
  if (xcopy) {
    f16x4 c;
    c[0] = (f16)v.x; c[1] = (f16)v.y; c[2] = (f16)v.z; c[3] = (f16)v.w;
    ((f16x4*)(xcopy + (size_t)row * HDIM))[t] = c;
  }
}

// -------- LayerNorm f16 in -> f16 out, 128 thr/row, f16x8 loads --------
__global__ __launch_bounds__(128) void ln_k16(const f16* __restrict__ x,
                                              const float* __restrict__ w,
                                              const float* __restrict__ b,
                                              f16* __restrict__ out) {
  int row = blockIdx.x;
  int t = threadIdx.x;  // 0..127
  f16x8 xv = ((const f16x8*)(x + (size_t)row * HDIM))[t];
  float v[8];
  float s = 0.f, s2 = 0.f;
#pragma unroll
  for (int i = 0; i < 8; i++) {
    v[i] = (float)xv[i];
    s += v[i]; s2 += v[i] * v[i];
  }
#pragma unroll
  for (int off = 32; off > 0; off >>= 1) {
    s  += __shfl_down(s, off);
    s2 += __shfl_down(s2, off);
  }
  __shared__ float red[4];
  int wid = t >> 6, lane = t & 63;
  if (lane == 0) { red[wid] = s; red[2 + wid] = s2; }
  __syncthreads();
  float mean = (red[0] + red[1]) * (1.0f / HDIM);
  float var  = (red[2] + red[3]) * (1.0f / HDIM) - mean * mean;
  float rstd = rsqrtf(var + 1e-5f);
  float4 w1 = ((const float4*)w)[2 * t], w2 = ((const float4*)w)[2 * t + 1];
  float4 b1 = ((const float4*)b)[2 * t], b2 = ((const float4*)b)[2 * t + 1];
  float wv[8] = {w1.x, w1.y, w1.z, w1.w, w2.x, w2.y, w2.z, w2.w};
  float bv[8] = {b1.x, b1.y, b1.z, b1.w, b2.x, b2.y, b2.z, b2.w};
  f16x8 o;
#pragma unroll
  for (int i = 0; i < 8; i++) o[i] = (f16)((v[i] - mean) * rstd * wv[i] + bv[i]);
  ((f16x8*)(out + (size_t)row * HDIM))[t] = o;
}

// -------- GEMM: C[M,N] = act(A[M,K] @ BT[N,K]^T + bias) (+f16 resid) --------
// R14 = R13 (verified 578.4us: 256x256, 8 waves, 2 interleaved phases,
// counted vmcnt, swizzle, setprio, vector epilogue) with ASYMMETRIC BUFFERS
// to restore 2 blocks/CU (R13's 96KB -> 1 blk/CU exposed prologue/epilogue
// serially; MfmaUtil 24%, occupancy 21%):
//   A: 3 buffers (48KB), distance 2 — HBM-latency streaming operand.
//   B: 2 buffers (32KB), distance 1 issued EARLY (phase 0) — L2-resident
//      4MB weight panel, ~1 iter (~450cy) of cover suffices.
//   Total 80KB x 2 blocks = 160KB exact. launch_bounds(512,4): VGPR cap 128
//   >= 96 used -> 16 waves/CU, inter-block overlap of fill/drain returns.
// Iter t: top vmcnt(2) [only A(t+2)'s 2 loads newer than needed B(t+1)] +
// barrier; phase0: ds_read A0-3+B, issue B(t+1)->Bs[(t+1)&1], bar, lgkm0,
// 16 MFMA; phase1: ds_read A4-7, issue A(t+2)->As[(t+2)%3], bar, lgkm0,
// 16 MFMA. Prologue order A(0),B(0),A(1) makes vmcnt(2) uniform from t=0;
// vmcnt(0) only at t=nt-1.
// WAR: Bs[(t+1)&1] holds B(t-1), last read iter t-1 phase0, covered by iter
// t top barrier; As[(t+2)%3] holds A(t-1), same coverage. RAW: counted wait
// + barrier (R13-verified pattern).
// MODE: 0=none 2=silu 3=ug-split. XCD-banded 1-D grid swizzle.
template <int MODE, int RESID, int OUTF16>
__global__ __launch_bounds__(512, 4) void gemm256(const f16* __restrict__ A,
                                                  const f16* __restrict__ BT,
                                                  const float* __restrict__ bias,
                                                  const float* __restrict__ bias2,
                                                  const f16* __restrict__ resid,
                                                  void* __restrict__ Cout,
                                                  void* __restrict__ Cout2,
                                                  int M, int N, int K) {
  __shared__ __align__(16) f16 As[3][256 * 32];   // 3 x 16KB
  __shared__ __align__(16) f16 Bs[2][256 * 32];   // 2 x 16KB
  const int tid  = threadIdx.x;
  const int lane = tid & 63;
  const int wid  = tid >> 6;                 // 8 waves
  const int wm = wid >> 2, wn = wid & 3;     // 2 x 4 wave grid
  const int quad = lane >> 4, l16 = lane & 15;
  const int xq = (quad ^ ((l16 >> 1) & 3)) << 4;   // swizzled 16B slot (bytes)

  // XCD-banded swizzle over 256x256 tiles
  const int nbx = N >> 8, nby = M >> 8;
  const int b = blockIdx.x;
  const int xcd = b & 7;
  const int i = b >> 3;
  const int strips = nby >> 3;               // row strips per XCD
  const int rs = i / nbx, cb = i - rs * nbx;
  const long m0 = (long)(xcd * strips + rs) << 8;
  const long n0 = (long)cb << 8;

  // staging: unit = 128 rows x 32 k = 8KB = 512 thr x 16B (1 load each).
  // dest row = tid>>2, phys slot = tid&3; logical source slot pre-swizzled:
  // qs = (tid&3) ^ ((row>>1)&3) = (tid&3) ^ ((tid>>3)&3)   (rule #21)
  const int srow = tid >> 2;
  const int qs = (tid & 3) ^ ((tid >> 3) & 3);
  const f16* gA = A  + (size_t)(m0 + srow) * K + qs * 8;
  const f16* gB = BT + (size_t)(n0 + srow) * K + qs * 8;
  const int sdst = tid * 16;                 // byte offset within an 8KB unit

  f32x4 zero = {0.f, 0.f, 0.f, 0.f};
  f32x4 acc[8][4];
#pragma unroll
  for (int mi = 0; mi < 8; ++mi)
#pragma unroll
    for (int ni = 0; ni < 4; ++ni) acc[mi][ni] = zero;

  // prologue: A(0), B(0), A(1)  (order matters for the uniform vmcnt(2))
#pragma unroll
  for (int h = 0; h < 2; ++h)
    __builtin_amdgcn_global_load_lds(AS1(gA + (size_t)h * 128 * K),
                                     AS3((char*)As[0] + h * 8192 + sdst), 16, 0, 0);
#pragma unroll
  for (int h = 0; h < 2; ++h)
    __builtin_amdgcn_global_load_lds(AS1(gB + (size_t)h * 128 * K),
                                     AS3((char*)Bs[0] + h * 8192 + sdst), 16, 0, 0);
#pragma unroll
  for (int h = 0; h < 2; ++h)
    __builtin_amdgcn_global_load_lds(AS1(gA + (size_t)h * 128 * K + 32),
                                     AS3((char*)As[1] + h * 8192 + sdst), 16, 0, 0);

  const int nt = K >> 5;
  int cur = 0;                               // t % 3 (A buffer index)
  for (int t = 0; t < nt; ++t) {
    // counted wait: newest needed op is B(t) (for t>0: issued iter t-1
    // phase0) or prologue B(0); only A(t+1)'s 2 loads are newer.
    if (t < nt - 1) asm volatile("s_waitcnt vmcnt(2)" ::: "memory");
    else            asm volatile("s_waitcnt vmcnt(0)" ::: "memory");
    __builtin_amdgcn_sched_barrier(0);
    __builtin_amdgcn_s_barrier();
    const f16* Ab = As[cur];
    const f16* Bb = Bs[t & 1];
    const int stgA = (cur + 2 >= 3) ? cur - 1 : cur + 2;   // (t+2)%3

    // ---- phase 0: A-frags mi 0-3 + all B-frags; stage B of t+1 (early) ----
    f16x8 af[4], bf[4];
#pragma unroll
    for (int mi = 0; mi < 4; ++mi) {
      const int row = wm * 128 + mi * 16 + l16;
      af[mi] = *(const f16x8*)((const char*)Ab + row * 64 + xq);
    }
#pragma unroll
    for (int ni = 0; ni < 4; ++ni) {
      const int row = wn * 64 + ni * 16 + l16;
      bf[ni] = *(const f16x8*)((const char*)Bb + row * 64 + xq);
    }
    if (t + 1 < nt) {
      const size_t koff = (size_t)(t + 1) * 32;
#pragma unroll
      for (int h = 0; h < 2; ++h)
        __builtin_amdgcn_global_load_lds(AS1(gB + (size_t)h * 128 * K + koff),
                                         AS3((char*)Bs[(t + 1) & 1] + h * 8192 + sdst), 16, 0, 0);
    }
    __builtin_amdgcn_s_barrier();
    asm volatile("s_waitcnt lgkmcnt(0)" ::: "memory");
    __builtin_amdgcn_sched_barrier(0);
    __builtin_amdgcn_s_setprio(1);
#pragma unroll
    for (int mi = 0; mi < 4; ++mi)
#pragma unroll
      for (int ni = 0; ni < 4; ++ni)
        acc[mi][ni] = __builtin_amdgcn_mfma_f32_16x16x32_f16(bf[ni], af[mi], acc[mi][ni], 0, 0, 0);
    __builtin_amdgcn_s_setprio(0);
    __builtin_amdgcn_sched_barrier(0);
    __builtin_amdgcn_s_barrier();

    // ---- phase 1: A-frags mi 4-7 (B held in regs); stage A of t+2 ----
    f16x8 af2[4];
#pragma unroll
    for (int mi = 0; mi < 4; ++mi) {
      const int row = wm * 128 + (4 + mi) * 16 + l16;
      af2[mi] = *(const f16x8*)((const char*)Ab + row * 64 + xq);
    }
    if (t + 2 < nt) {
      const size_t koff = (size_t)(t + 2) * 32;
#pragma unroll
      for (int h = 0; h < 2; ++h)
        __builtin_amdgcn_global_load_lds(AS1(gA + (size_t)h * 128 * K + koff),
                                         AS3((char*)As[stgA] + h * 8192 + sdst), 16, 0, 0);
    }
    __builtin_amdgcn_s_barrier();
    asm volatile("s_waitcnt lgkmcnt(0)" ::: "memory");
    __builtin_amdgcn_sched_barrier(0);
    __builtin_amdgcn_s_setprio(1);
#pragma unroll
    for (int mi = 0; mi < 4; ++mi)
#pragma unroll
      for (int ni = 0; ni < 4; ++ni)
        acc[4 + mi][ni] = __builtin_amdgcn_mfma_f32_16x16x32_f16(bf[ni], af2[mi], acc[4 + mi][ni], 0, 0, 0);
    __builtin_amdgcn_s_setprio(0);
    __builtin_amdgcn_sched_barrier(0);
    // no trailing barrier: next iter-top vmcnt+barrier covers WAR/RAW
    cur = (cur == 2) ? 0 : cur + 1;
  }

  // epilogue (R11-verified transposed mapping): row fixed per (mi,l16),
  // 4 consecutive cols per (ni,quad) -> vector stores.
#pragma unroll
  for (int mi = 0; mi < 8; ++mi) {
    const long row = m0 + wm * 128 + mi * 16 + l16;
#pragma unroll
    for (int ni = 0; ni < 4; ++ni) {
      const long col = n0 + wn * 64 + ni * 16 + quad * 4;   // %4 == 0
      const float* bp;
      if (MODE == 3) bp = (col < HDIM) ? (bias + col) : (bias2 + (col - HDIM));
      else           bp = bias + col;
      f32x4 v = acc[mi][ni] + *(const f32x4*)bp;
      if (MODE == 2) {
#pragma unroll
        for (int r = 0; r < 4; ++r) v[r] = v[r] / (1.f + __expf(-v[r]));
      }
      if (MODE == 3) {
        if (col < HDIM) {
          f16x4 o;
#pragma unroll
          for (int r = 0; r < 4; ++r) o[r] = (f16)v[r];
          *(f16x4*)((f16*)Cout + row * HDIM + col) = o;
        } else {
          f16x4 o;
#pragma unroll
          for (int r = 0; r < 4; ++r) o[r] = (f16)(1.f / (1.f + __expf(-v[r])));
          *(f16x4*)((f16*)Cout2 + row * HDIM + (col - HDIM)) = o;
        }
      } else {
        if (RESID) {
          f16x4 rv = *(const f16x4*)(resid + row * N + col);
#pragma unroll
          for (int r = 0; r < 4; ++r) v[r] += (float)rv[r];
        }
        if (OUTF16) {
          f16x4 o;
#pragma unroll
          for (int r = 0; r < 4; ++r) o[r] = (f16)v[r];
          *(f16x4*)((f16*)Cout + row * N + col) = o;
        } else {
          *(f32x4*)((float*)Cout + row * N + col) = v;
        }
      }
    }
  }
}

// -------- scan pass 1: per-chunk local fwd & bwd carries (one read pass) ----
__global__ __launch_bounds__(256) void scan_p1(const f16* __restrict__ u,
                                               const float* __restrict__ sdecay,
                                               float* __restrict__ carry_f,
                                               float* __restrict__ carry_b) {
  int tid = blockIdx.x * 256 + threadIdx.x;
  int h = tid & (HDIM - 1);
  int c = tid >> 10;
  float d = 1.f / (1.f + expf(-sdecay[h]));
  const f16* up = u + (size_t)c * CH * HDIM + h;
  float sf = 0.f, sb = 0.f, p = 1.f;
#pragma unroll
  for (int i = 0; i < CH; i++) {
    float uu = (float)up[i * HDIM];
    sf = d * sf + uu;   // local fwd final
    sb += p * uu;       // local bwd final = sum d^i * u_i
    p *= d;
  }
  carry_f[(size_t)c * HDIM + h] = sf;
  carry_b[(size_t)c * HDIM + h] = sb;
}

// -------- scan pass 2: chunk-level exclusive scans (fwd dir=0, bwd dir=1) --
__global__ __launch_bounds__(256) void scan_p2(const float* __restrict__ sdecay,
                                               const float* __restrict__ carry_f,
                                               const float* __restrict__ carry_b,
                                               float* __restrict__ cin_f,
                                               float* __restrict__ cin_b) {
  int tid = blockIdx.x * 256 + threadIdx.x;  // 2048 threads
  int h = tid & (HDIM - 1);
  int dir = tid >> 10;
  float d = 1.f / (1.f + expf(-sdecay[h]));
  float dT = powf(d, (float)CH);
  float S = 0.f;
  if (dir == 0) {
#pragma unroll 4
    for (int c = 0; c < NC; c++) {
      cin_f[(size_t)c * HDIM + h] = S;
      S = dT * S + carry_f[(size_t)c * HDIM + h];
    }
  } else {
#pragma unroll 4
    for (int c = NC - 1; c >= 0; c--) {
      cin_b[(size_t)c * HDIM + h] = S;
      S = dT * S + carry_b[(size_t)c * HDIM + h];
    }
  }
}

// -------- scan pass 3: re-scan chunk with carries, fuse gate, f16 out ------
__global__ __launch_bounds__(256) void scan_p3(const f16* __restrict__ u,
                                               const f16* __restrict__ gate,
                                               const float* __restrict__ sdecay,
                                               const float* __restrict__ cin_f,
                                               const float* __restrict__ cin_b,
                                               f16* __restrict__ state_out) {
  int tid = blockIdx.x * 256 + threadIdx.x;
  int h = tid & (HDIM - 1);
  int c = tid >> 10;
  float d = 1.f / (1.f + expf(-sdecay[h]));
  const f16* up = u    + (size_t)c * CH * HDIM + h;
  const f16* gp = gate + (size_t)c * CH * HDIM + h;
  f16* op = state_out  + (size_t)c * CH * HDIM + h;
  float ur[CH], sf[CH];
#pragma unroll
  for (int i = 0; i < CH; i++) ur[i] = (float)up[i * HDIM];
  float s = cin_f[(size_t)c * HDIM + h];
#pragma unroll
  for (int i = 0; i < CH; i++) { s = d * s + ur[i]; sf[i] = s; }
  s = cin_b[(size_t)c * HDIM + h];
#pragma unroll
  for (int i = CH - 1; i >= 0; i--) {
    s = d * s + ur[i];
    float g = (float)gp[i * HDIM];
    op[i * HDIM] = (f16)(0.5f * (sf[i] + s) * g);
  }
}

extern "C" void kernel_launch(void* const* d_in, const int* in_sizes, int n_in,
                              void* d_out, int out_size, void* d_ws, size_t ws_size,
                              hipStream_t stream) {
  const float* x      = (const float*)d_in[0];
  const float* ln1_w  = (const float*)d_in[1];
  const float* ln1_b  = (const float*)d_in[2];
  const float* W_in   = (const float*)d_in[3];
  const float* b_in   = (const float*)d_in[4];
  const float* W_gate = (const float*)d_in[5];
  const float* b_gate = (const float*)d_in[6];
  const float* W_out  = (const float*)d_in[7];
  const float* b_out  = (const float*)d_in[8];
  const float* sdecay = (const float*)d_in[9];
  const float* ln2_w  = (const float*)d_in[10];
  const float* ln2_b  = (const float*)d_in[11];
  const float* W_ff1  = (const float*)d_in[12];
  const float* b_ff1  = (const float*)d_in[13];
  const float* W_ff2  = (const float*)d_in[14];
  const float* b_ff2  = (const float*)d_in[15];
  float* out = (float*)d_out;

  char* ws = (char*)d_ws;
  const size_t MB32 = 33554432, MB64 = 67108864;
  f16* hidden = (f16*)(ws);                 // 32MB; reused as state_out
  f16* xh     = (f16*)(ws + MB32);          // 32MB f16 copy of x
  f16* u      = (f16*)(ws + 2 * MB32);      // 32MB; reused as h2
  f16* gate   = (f16*)(ws + 3 * MB32);      // 32MB
  f16* x2h    = (f16*)(ws + 4 * MB32);      // 32MB f16 x2
  f16* ff     = (f16*)(ws + 5 * MB32);      // 64MB
  char* wbase = ws + 5 * MB32 + MB64;
  f16* wt_ug  = (f16*)(wbase);                       // 4MB (2048x1024)
  f16* wt_out = (f16*)(wbase + 4194304);             // 2MB
  f16* wt_ff1 = (f16*)(wbase + 4194304 + 2097152);   // 4MB
  f16* wt_ff2 = (f16*)(wbase + 2 * 4194304 + 2097152); // 4MB
  char* cbase = wbase + 3 * 4194304 + 2097152;
  float* carry_f = (float*)(cbase);
  float* carry_b = (float*)(cbase + 2097152);
  float* cin_f   = (float*)(cbase + 2 * 2097152);
  float* cin_b   = (float*)(cbase + 3 * 2097152);
  f16* state_out = hidden;  // hidden dead after fused u/gate GEMM
  f16* h2        = u;       // u dead after scan_p3

  dim3 tb(32, 8);
  wcvt_t<<<dim3(32, 32), tb, 0, stream>>>(W_in,   wt_ug,                 1024, 1024);
  wcvt_t<<<dim3(32, 32), tb, 0, stream>>>(W_gate, wt_ug + 1024 * 1024,   1024, 1024);
  wcvt_t<<<dim3(32, 32), tb, 0, stream>>>(W_out,  wt_out,                1024, 1024);
  wcvt_t<<<dim3(64, 32), tb, 0, stream>>>(W_ff1,  wt_ff1,                1024, 2048);
  wcvt_t<<<dim3(32, 64), tb, 0, stream>>>(W_ff2,  wt_ff2,                2048, 1024);

  ln_k<<<L_SEQ, 256, 0, stream>>>(x, ln1_w, ln1_b, hidden, xh);

  // fused u + gate: N=2048  (64x8 = 512 tiles of 256x256)
  gemm256<3, 0, 1><<<512, 512, 0, stream>>>(hidden, wt_ug, b_in, b_gate, nullptr,
                                            u, gate, L_SEQ, 2048, 1024);

  scan_p1<<<2048, 256, 0, stream>>>(u, sdecay, carry_f, carry_b);
  scan_p2<<<8, 256, 0, stream>>>(sdecay, carry_f, carry_b, cin_f, cin_b);
  scan_p3<<<2048, 256, 0, stream>>>(u, gate, sdecay, cin_f, cin_b, state_out);

  // x2 = x + state_out @ W_out + b_out  (f16 out)  (64x4 = 256 tiles)
  gemm256<0, 1, 1><<<256, 512, 0, stream>>>(state_out, wt_out, b_out, nullptr, xh,
                                            x2h, nullptr, L_SEQ, 1024, 1024);

  ln_k16<<<L_SEQ, 128, 0, stream>>>(x2h, ln2_w, ln2_b, h2);

  gemm256<2, 0, 1><<<512, 512, 0, stream>>>(h2, wt_ff1, b_ff1, nullptr, nullptr,
                                            ff, nullptr, L_SEQ, 2048, 1024);

  // out = x2 + silu(h2@W_ff1) @ W_ff2 + b_ff2  (fp32 out)  (64x4 = 256 tiles)
  gemm256<0, 1, 0><<<256, 512, 0, stream>>>(ff, wt_ff2, b_ff2, nullptr, x2h,
                                            out, nullptr, L_SEQ, 1024, 2048);
}

// Round 10
// 578.378 us; speedup vs baseline: 3.8437x; 3.8437x over previous
//
#include <hip/hip_runtime.h>
#include <hip/hip_bf16.h>
#include <hip/hip_fp16.h>

#define L_SEQ 16384
#define HDIM  1024
#define CH    32
#define NC    (L_SEQ / CH)   // 512 chunks

typedef _Float16 f16;
typedef _Float16 f16x8 __attribute__((ext_vector_type(8)));
typedef _Float16 f16x4 __attribute__((ext_vector_type(4)));
typedef float    f32x4 __attribute__((ext_vector_type(4)));

#define AS1(p) (const __attribute__((address_space(1))) void*)(p)
#define AS3(p) (__attribute__((address_space(3))) void*)(p)

// -------- weight convert + transpose: out[n*K+k] = (f16) in[k*N+n] --------
__global__ __launch_bounds__(256) void wcvt_t(const float* __restrict__ in,
                                              f16* __restrict__ out, int K, int N) {
  __shared__ float tile[32][33];
  int n0 = blockIdx.x * 32, k0 = blockIdx.y * 32;
  int tx = threadIdx.x, ty = threadIdx.y;  // (32,8)
#pragma unroll
  for (int i = 0; i < 4; i++) {
    int k = k0 + ty + i * 8;
    tile[ty + i * 8][tx] = in[(size_t)k * N + n0 + tx];
  }
  __syncthreads();
#pragma unroll
  for (int i = 0; i < 4; i++) {
    int n = n0 + ty + i * 8;
    out[(size_t)n * K + k0 + tx] = (f16)tile[tx][ty + i * 8];
  }
}

// -------- LayerNorm fp32 in -> f16 out (+ optional f16 copy of input) -----
__global__ __launch_bounds__(256) void ln_k(const float* __restrict__ x,
                                            const float* __restrict__ w,
                                            const float* __restrict__ b,
                                            f16* __restrict__ out,
                                            f16* __restrict__ xcopy) {
  int row = blockIdx.x;
  int t = threadIdx.x;
  const float4* xr = (const float4*)(x + (size_t)row * HDIM);
  float4 v = xr[t];
  float s  = v.x + v.y + v.z + v.w;
  float s2 = v.x * v.x + v.y * v.y + v.z * v.z + v.w * v.w;
#pragma unroll
  for (int off = 32; off > 0; off >>= 1) {
    s  += __shfl_down(s, off);
    s2 += __shfl_down(s2, off);
  }
  __shared__ float red[8];
  int wid = t >> 6, lane = t & 63;
  if (lane == 0) { red[wid] = s; red[4 + wid] = s2; }
  __syncthreads();
  if (t == 0) {
    red[0] = red[0] + red[1] + red[2] + red[3];
    red[4] = red[4] + red[5] + red[6] + red[7];
  }
  __syncthreads();
  float mean = red[0] * (1.0f / HDIM);
  float var  = red[4] * (1.0f / HDIM) - mean * mean;
  float rstd = rsqrtf(var + 1e-5f);
  float4 ww = ((const float4*)w)[t];
  float4 bb = ((const float4*)b)[t];
  f16x4 o;
  o[0] = (f16)((v.x - mean) * rstd * ww.x + bb.x);
  o[1] = (f16)((v.y - mean) * rstd * ww.y + bb.y);
  o[2] = (f16)((v.z - mean) * rstd * ww.z + bb.z);
  o[3] = (f16)((v.w - mean) * rstd * ww.w + bb.w);
  ((f16x4*)(out + (size_t)row * HDIM))[t] = o;
  if (xcopy) {
    f16x4 c;
    c[0] = (f16)v.x; c[1] = (f16)v.y; c[2] = (f16)v.z; c[3] = (f16)v.w;
    ((f16x4*)(xcopy + (size_t)row * HDIM))[t] = c;
  }
}

// -------- LayerNorm f16 in -> f16 out, 128 thr/row, f16x8 loads --------
__global__ __launch_bounds__(128) void ln_k16(const f16* __restrict__ x,
                                              const float* __restrict__ w,
                                              const float* __restrict__ b,
                                              f16* __restrict__ out) {
  int row = blockIdx.x;
  int t = threadIdx.x;  // 0..127
  f16x8 xv = ((const f16x8*)(x + (size_t)row * HDIM))[t];
  float v[8];
  float s = 0.f, s2 = 0.f;
#pragma unroll
  for (int i = 0; i < 8; i++) {
    v[i] = (float)xv[i];
    s += v[i]; s2 += v[i] * v[i];
  }
#pragma unroll
  for (int off = 32; off > 0; off >>= 1) {
    s  += __shfl_down(s, off);
    s2 += __shfl_down(s2, off);
  }
  __shared__ float red[4];
  int wid = t >> 6, lane = t & 63;
  if (lane == 0) { red[wid] = s; red[2 + wid] = s2; }
  __syncthreads();
  float mean = (red[0] + red[1]) * (1.0f / HDIM);
  float var  = (red[2] + red[3]) * (1.0f / HDIM) - mean * mean;
  float rstd = rsqrtf(var + 1e-5f);
  float4 w1 = ((const float4*)w)[2 * t], w2 = ((const float4*)w)[2 * t + 1];
  float4 b1 = ((const float4*)b)[2 * t], b2 = ((const float4*)b)[2 * t + 1];
  float wv[8] = {w1.x, w1.y, w1.z, w1.w, w2.x, w2.y, w2.z, w2.w};
  float bv[8] = {b1.x, b1.y, b1.z, b1.w, b2.x, b2.y, b2.z, b2.w};
  f16x8 o;
#pragma unroll
  for (int i = 0; i < 8; i++) o[i] = (f16)((v[i] - mean) * rstd * wv[i] + bv[i]);
  ((f16x8*)(out + (size_t)row * HDIM))[t] = o;
}

// -------- GEMM: C[M,N] = act(A[M,K] @ BT[N,K]^T + bias) (+f16 resid) --------
// R15 = R14's asymmetric-buffer schedule with the VGPR-spill bug fixed:
// launch_bounds back to (512,2) — R14's (512,4) capped the allocator at 64
// VGPR (acc alone needs 128) -> 1.8GB scratch writes, 5x regression.
// At (512,2) the compiler allocates ~96-110 VGPR (R12/R13 precedent, no
// spill); occupancy is then LDS-limited at EXACTLY 2 blocks/CU
// (2 x 80KB = 160KB), restoring inter-block fill/drain overlap that R13's
// 96KB (1 blk/CU) lost, while keeping the counted-vmcnt pipeline:
//   A: 3 buffers (48KB), distance 2 — HBM-latency streaming operand.
//   B: 2 buffers (32KB), distance 1 issued EARLY (phase 0) — L2-resident
//      weight panel, ~1 iter (~450cy) of cover suffices.
// Iter t: top vmcnt(2) [only A(t+2)'s 2 loads newer than needed B(t)] +
// barrier; phase0: ds_read A0-3+B, issue B(t+1)->Bs[(t+1)&1], bar, lgkm0,
// 16 MFMA; phase1: ds_read A4-7, issue A(t+2)->As[(t+2)%3], bar, lgkm0,
// 16 MFMA. Prologue order A(0),B(0),A(1) makes vmcnt(2) uniform from t=0;
// vmcnt(0) only at t=nt-1.
// WAR: Bs[(t+1)&1] holds B(t-1), last read iter t-1 phase0, covered by iter
// t top barrier; As[(t+2)%3] holds A(t-1), same coverage. RAW: counted wait
// + barrier (R13-verified pattern).
// MODE: 0=none 2=silu 3=ug-split. XCD-banded 1-D grid swizzle.
template <int MODE, int RESID, int OUTF16>
__global__ __launch_bounds__(512, 2) void gemm256(const f16* __restrict__ A,
                                                  const f16* __restrict__ BT,
                                                  const float* __restrict__ bias,
                                                  const float* __restrict__ bias2,
                                                  const f16* __restrict__ resid,
                                                  void* __restrict__ Cout,
                                                  void* __restrict__ Cout2,
                                                  int M, int N, int K) {
  __shared__ __align__(16) f16 As[3][256 * 32];   // 3 x 16KB
  __shared__ __align__(16) f16 Bs[2][256 * 32];   // 2 x 16KB
  const int tid  = threadIdx.x;
  const int lane = tid & 63;
  const int wid  = tid >> 6;                 // 8 waves
  const int wm = wid >> 2, wn = wid & 3;     // 2 x 4 wave grid
  const int quad = lane >> 4, l16 = lane & 15;
  const int xq = (quad ^ ((l16 >> 1) & 3)) << 4;   // swizzled 16B slot (bytes)

  // XCD-banded swizzle over 256x256 tiles
  const int nbx = N >> 8, nby = M >> 8;
  const int b = blockIdx.x;
  const int xcd = b & 7;
  const int i = b >> 3;
  const int strips = nby >> 3;               // row strips per XCD
  const int rs = i / nbx, cb = i - rs * nbx;
  const long m0 = (long)(xcd * strips + rs) << 8;
  const long n0 = (long)cb << 8;

  // staging: unit = 128 rows x 32 k = 8KB = 512 thr x 16B (1 load each).
  // dest row = tid>>2, phys slot = tid&3; logical source slot pre-swizzled:
  // qs = (tid&3) ^ ((row>>1)&3) = (tid&3) ^ ((tid>>3)&3)   (rule #21)
  const int srow = tid >> 2;
  const int qs = (tid & 3) ^ ((tid >> 3) & 3);
  const f16* gA = A  + (size_t)(m0 + srow) * K + qs * 8;
  const f16* gB = BT + (size_t)(n0 + srow) * K + qs * 8;
  const int sdst = tid * 16;                 // byte offset within an 8KB unit

  f32x4 zero = {0.f, 0.f, 0.f, 0.f};
  f32x4 acc[8][4];
#pragma unroll
  for (int mi = 0; mi < 8; ++mi)
#pragma unroll
    for (int ni = 0; ni < 4; ++ni) acc[mi][ni] = zero;

  // prologue: A(0), B(0), A(1)  (order matters for the uniform vmcnt(2))
#pragma unroll
  for (int h = 0; h < 2; ++h)
    __builtin_amdgcn_global_load_lds(AS1(gA + (size_t)h * 128 * K),
                                     AS3((char*)As[0] + h * 8192 + sdst), 16, 0, 0);
#pragma unroll
  for (int h = 0; h < 2; ++h)
    __builtin_amdgcn_global_load_lds(AS1(gB + (size_t)h * 128 * K),
                                     AS3((char*)Bs[0] + h * 8192 + sdst), 16, 0, 0);
#pragma unroll
  for (int h = 0; h < 2; ++h)
    __builtin_amdgcn_global_load_lds(AS1(gA + (size_t)h * 128 * K + 32),
                                     AS3((char*)As[1] + h * 8192 + sdst), 16, 0, 0);

  const int nt = K >> 5;
  int cur = 0;                               // t % 3 (A buffer index)
  for (int t = 0; t < nt; ++t) {
    // counted wait: newest needed op is B(t) (for t>0: issued iter t-1
    // phase0) or prologue B(0); only A(t+1)'s 2 loads are newer.
    if (t < nt - 1) asm volatile("s_waitcnt vmcnt(2)" ::: "memory");
    else            asm volatile("s_waitcnt vmcnt(0)" ::: "memory");
    __builtin_amdgcn_sched_barrier(0);
    __builtin_amdgcn_s_barrier();
    const f16* Ab = As[cur];
    const f16* Bb = Bs[t & 1];
    const int stgA = (cur + 2 >= 3) ? cur - 1 : cur + 2;   // (t+2)%3

    // ---- phase 0: A-frags mi 0-3 + all B-frags; stage B of t+1 (early) ----
    f16x8 af[4], bf[4];
#pragma unroll
    for (int mi = 0; mi < 4; ++mi) {
      const int row = wm * 128 + mi * 16 + l16;
      af[mi] = *(const f16x8*)((const char*)Ab + row * 64 + xq);
    }
#pragma unroll
    for (int ni = 0; ni < 4; ++ni) {
      const int row = wn * 64 + ni * 16 + l16;
      bf[ni] = *(const f16x8*)((const char*)Bb + row * 64 + xq);
    }
    if (t + 1 < nt) {
      const size_t koff = (size_t)(t + 1) * 32;
#pragma unroll
      for (int h = 0; h < 2; ++h)
        __builtin_amdgcn_global_load_lds(AS1(gB + (size_t)h * 128 * K + koff),
                                         AS3((char*)Bs[(t + 1) & 1] + h * 8192 + sdst), 16, 0, 0);
    }
    __builtin_amdgcn_s_barrier();
    asm volatile("s_waitcnt lgkmcnt(0)" ::: "memory");
    __builtin_amdgcn_sched_barrier(0);
    __builtin_amdgcn_s_setprio(1);
#pragma unroll
    for (int mi = 0; mi < 4; ++mi)
#pragma unroll
      for (int ni = 0; ni < 4; ++ni)
        acc[mi][ni] = __builtin_amdgcn_mfma_f32_16x16x32_f16(bf[ni], af[mi], acc[mi][ni], 0, 0, 0);
    __builtin_amdgcn_s_setprio(0);
    __builtin_amdgcn_sched_barrier(0);
    __builtin_amdgcn_s_barrier();

    // ---- phase 1: A-frags mi 4-7 (B held in regs); stage A of t+2 ----
    f16x8 af2[4];
#pragma unroll
    for (int mi = 0; mi < 4; ++mi) {
      const int row = wm * 128 + (4 + mi) * 16 + l16;
      af2[mi] = *(const f16x8*)((const char*)Ab + row * 64 + xq);
    }
    if (t + 2 < nt) {
      const size_t koff = (size_t)(t + 2) * 32;
#pragma unroll
      for (int h = 0; h < 2; ++h)
        __builtin_amdgcn_global_load_lds(AS1(gA + (size_t)h * 128 * K + koff),
                                         AS3((char*)As[stgA] + h * 8192 + sdst), 16, 0, 0);
    }
    __builtin_amdgcn_s_barrier();
    asm volatile("s_waitcnt lgkmcnt(0)" ::: "memory");
    __builtin_amdgcn_sched_barrier(0);
    __builtin_amdgcn_s_setprio(1);
#pragma unroll
    for (int mi = 0; mi < 4; ++mi)
#pragma unroll
      for (int ni = 0; ni < 4; ++ni)
        acc[4 + mi][ni] = __builtin_amdgcn_mfma_f32_16x16x32_f16(bf[ni], af2[mi], acc[4 + mi][ni], 0, 0, 0);
    __builtin_amdgcn_s_setprio(0);
    __builtin_amdgcn_sched_barrier(0);
    // no trailing barrier: next iter-top vmcnt+barrier covers WAR/RAW
    cur = (cur == 2) ? 0 : cur + 1;
  }

  // epilogue (R11-verified transposed mapping): row fixed per (mi,l16),
  // 4 consecutive cols per (ni,quad) -> vector stores.
#pragma unroll
  for (int mi = 0; mi < 8; ++mi) {
    const long row = m0 + wm * 128 + mi * 16 + l16;
#pragma unroll
    for (int ni = 0; ni < 4; ++ni) {
      const long col = n0 + wn * 64 + ni * 16 + quad * 4;   // %4 == 0
      const float* bp;
      if (MODE == 3) bp = (col < HDIM) ? (bias + col) : (bias2 + (col - HDIM));
      else           bp = bias + col;
      f32x4 v = acc[mi][ni] + *(const f32x4*)bp;
      if (MODE == 2) {
#pragma unroll
        for (int r = 0; r < 4; ++r) v[r] = v[r] / (1.f + __expf(-v[r]));
      }
      if (MODE == 3) {
        if (col < HDIM) {
          f16x4 o;
#pragma unroll
          for (int r = 0; r < 4; ++r) o[r] = (f16)v[r];
          *(f16x4*)((f16*)Cout + row * HDIM + col) = o;
        } else {
          f16x4 o;
#pragma unroll
          for (int r = 0; r < 4; ++r) o[r] = (f16)(1.f / (1.f + __expf(-v[r])));
          *(f16x4*)((f16*)Cout2 + row * HDIM + (col - HDIM)) = o;
        }
      } else {
        if (RESID) {
          f16x4 rv = *(const f16x4*)(resid + row * N + col);
#pragma unroll
          for (int r = 0; r < 4; ++r) v[r] += (float)rv[r];
        }
        if (OUTF16) {
          f16x4 o;
#pragma unroll
          for (int r = 0; r < 4; ++r) o[r] = (f16)v[r];
          *(f16x4*)((f16*)Cout + row * N + col) = o;
        } else {
          *(f32x4*)((float*)Cout + row * N + col) = v;
        }
      }
    }
  }
}

// -------- scan pass 1: per-chunk local fwd & bwd carries (one read pass) ----
__global__ __launch_bounds__(256) void scan_p1(const f16* __restrict__ u,
                                               const float* __restrict__ sdecay,
                                               float* __restrict__ carry_f,
                                               float* __restrict__ carry_b) {
  int tid = blockIdx.x * 256 + threadIdx.x;
  int h = tid & (HDIM - 1);
  int c = tid >> 10;
  float d = 1.f / (1.f + expf(-sdecay[h]));
  const f16* up = u + (size_t)c * CH * HDIM + h;
  float sf = 0.f, sb = 0.f, p = 1.f;
#pragma unroll
  for (int i = 0; i < CH; i++) {
    float uu = (float)up[i * HDIM];
    sf = d * sf + uu;   // local fwd final
    sb += p * uu;       // local bwd final = sum d^i * u_i
    p *= d;
  }
  carry_f[(size_t)c * HDIM + h] = sf;
  carry_b[(size_t)c * HDIM + h] = sb;
}

// -------- scan pass 2: chunk-level exclusive scans (fwd dir=0, bwd dir=1) --
__global__ __launch_bounds__(256) void scan_p2(const float* __restrict__ sdecay,
                                               const float* __restrict__ carry_f,
                                               const float* __restrict__ carry_b,
                                               float* __restrict__ cin_f,
                                               float* __restrict__ cin_b) {
  int tid = blockIdx.x * 256 + threadIdx.x;  // 2048 threads
  int h = tid & (HDIM - 1);
  int dir = tid >> 10;
  float d = 1.f / (1.f + expf(-sdecay[h]));
  float dT = powf(d, (float)CH);
  float S = 0.f;
  if (dir == 0) {
#pragma unroll 4
    for (int c = 0; c < NC; c++) {
      cin_f[(size_t)c * HDIM + h] = S;
      S = dT * S + carry_f[(size_t)c * HDIM + h];
    }
  } else {
#pragma unroll 4
    for (int c = NC - 1; c >= 0; c--) {
      cin_b[(size_t)c * HDIM + h] = S;
      S = dT * S + carry_b[(size_t)c * HDIM + h];
    }
  }
}

// -------- scan pass 3: re-scan chunk with carries, fuse gate, f16 out ------
__global__ __launch_bounds__(256) void scan_p3(const f16* __restrict__ u,
                                               const f16* __restrict__ gate,
                                               const float* __restrict__ sdecay,
                                               const float* __restrict__ cin_f,
                                               const float* __restrict__ cin_b,
                                               f16* __restrict__ state_out) {
  int tid = blockIdx.x * 256 + threadIdx.x;
  int h = tid & (HDIM - 1);
  int c = tid >> 10;
  float d = 1.f / (1.f + expf(-sdecay[h]));
  const f16* up = u    + (size_t)c * CH * HDIM + h;
  const f16* gp = gate + (size_t)c * CH * HDIM + h;
  f16* op = state_out  + (size_t)c * CH * HDIM + h;
  float ur[CH], sf[CH];
#pragma unroll
  for (int i = 0; i < CH; i++) ur[i] = (float)up[i * HDIM];
  float s = cin_f[(size_t)c * HDIM + h];
#pragma unroll
  for (int i = 0; i < CH; i++) { s = d * s + ur[i]; sf[i] = s; }
  s = cin_b[(size_t)c * HDIM + h];
#pragma unroll
  for (int i = CH - 1; i >= 0; i--) {
    s = d * s + ur[i];
    float g = (float)gp[i * HDIM];
    op[i * HDIM] = (f16)(0.5f * (sf[i] + s) * g);
  }
}

extern "C" void kernel_launch(void* const* d_in, const int* in_sizes, int n_in,
                              void* d_out, int out_size, void* d_ws, size_t ws_size,
                              hipStream_t stream) {
  const float* x      = (const float*)d_in[0];
  const float* ln1_w  = (const float*)d_in[1];
  const float* ln1_b  = (const float*)d_in[2];
  const float* W_in   = (const float*)d_in[3];
  const float* b_in   = (const float*)d_in[4];
  const float* W_gate = (const float*)d_in[5];
  const float* b_gate = (const float*)d_in[6];
  const float* W_out  = (const float*)d_in[7];
  const float* b_out  = (const float*)d_in[8];
  const float* sdecay = (const float*)d_in[9];
  const float* ln2_w  = (const float*)d_in[10];
  const float* ln2_b  = (const float*)d_in[11];
  const float* W_ff1  = (const float*)d_in[12];
  const float* b_ff1  = (const float*)d_in[13];
  const float* W_ff2  = (const float*)d_in[14];
  const float* b_ff2  = (const float*)d_in[15];
  float* out = (float*)d_out;

  char* ws = (char*)d_ws;
  const size_t MB32 = 33554432, MB64 = 67108864;
  f16* hidden = (f16*)(ws);                 // 32MB; reused as state_out
  f16* xh     = (f16*)(ws + MB32);          // 32MB f16 copy of x
  f16* u      = (f16*)(ws + 2 * MB32);      // 32MB; reused as h2
  f16* gate   = (f16*)(ws + 3 * MB32);      // 32MB
  f16* x2h    = (f16*)(ws + 4 * MB32);      // 32MB f16 x2
  f16* ff     = (f16*)(ws + 5 * MB32);      // 64MB
  char* wbase = ws + 5 * MB32 + MB64;
  f16* wt_ug  = (f16*)(wbase);                       // 4MB (2048x1024)
  f16* wt_out = (f16*)(wbase + 4194304);             // 2MB
  f16* wt_ff1 = (f16*)(wbase + 4194304 + 2097152);   // 4MB
  f16* wt_ff2 = (f16*)(wbase + 2 * 4194304 + 2097152); // 4MB
  char* cbase = wbase + 3 * 4194304 + 2097152;
  float* carry_f = (float*)(cbase);
  float* carry_b = (float*)(cbase + 2097152);
  float* cin_f   = (float*)(cbase + 2 * 2097152);
  float* cin_b   = (float*)(cbase + 3 * 2097152);
  f16* state_out = hidden;  // hidden dead after fused u/gate GEMM
  f16* h2        = u;       // u dead after scan_p3

  dim3 tb(32, 8);
  wcvt_t<<<dim3(32, 32), tb, 0, stream>>>(W_in,   wt_ug,                 1024, 1024);
  wcvt_t<<<dim3(32, 32), tb, 0, stream>>>(W_gate, wt_ug + 1024 * 1024,   1024, 1024);
  wcvt_t<<<dim3(32, 32), tb, 0, stream>>>(W_out,  wt_out,                1024, 1024);
  wcvt_t<<<dim3(64, 32), tb, 0, stream>>>(W_ff1,  wt_ff1,                1024, 2048);
  wcvt_t<<<dim3(32, 64), tb, 0, stream>>>(W_ff2,  wt_ff2,                2048, 1024);

  ln_k<<<L_SEQ, 256, 0, stream>>>(x, ln1_w, ln1_b, hidden, xh);

  // fused u + gate: N=2048  (64x8 = 512 tiles of 256x256)
  gemm256<3, 0, 1><<<512, 512, 0, stream>>>(hidden, wt_ug, b_in, b_gate, nullptr,
                                            u, gate, L_SEQ, 2048, 1024);

  scan_p1<<<2048, 256, 0, stream>>>(u, sdecay, carry_f, carry_b);
  scan_p2<<<8, 256, 0, stream>>>(sdecay, carry_f, carry_b, cin_f, cin_b);
  scan_p3<<<2048, 256, 0, stream>>>(u, gate, sdecay, cin_f, cin_b, state_out);

  // x2 = x + state_out @ W_out + b_out  (f16 out)  (64x4 = 256 tiles)
  gemm256<0, 1, 1><<<256, 512, 0, stream>>>(state_out, wt_out, b_out, nullptr, xh,
                                            x2h, nullptr, L_SEQ, 1024, 1024);

  ln_k16<<<L_SEQ, 128, 0, stream>>>(x2h, ln2_w, ln2_b, h2);

  gemm256<2, 0, 1><<<512, 512, 0, stream>>>(h2, wt_ff1, b_ff1, nullptr, nullptr,
                                            ff, nullptr, L_SEQ, 2048, 1024);

  // out = x2 + silu(h2@W_ff1) @ W_ff2 + b_ff2  (fp32 out)  (64x4 = 256 tiles)
  gemm256<0, 1, 0><<<256, 512, 0, stream>>>(ff, wt_ff2, b_ff2, nullptr, x2h,
                                            out, nullptr, L_SEQ, 1024, 2048);
}

// Round 12
// 569.394 us; speedup vs baseline: 3.9043x; 1.0158x over previous
//
#include <hip/hip_runtime.h>
#include <hip/hip_bf16.h>
#include <hip/hip_fp16.h>

#define L_SEQ 16384
#define HDIM  1024
#define CH    32
#define NC    (L_SEQ / CH)   // 512 chunks

typedef _Float16 f16;
typedef _Float16 f16x8 __attribute__((ext_vector_type(8)));
typedef _Float16 f16x4 __attribute__((ext_vector_type(4)));
typedef float    f32x4 __attribute__((ext_vector_type(4)));

#define AS1(p) (const __attribute__((address_space(1))) void*)(p)
#define AS3(p) (__attribute__((address_space(3))) void*)(p)

// -------- weight convert + transpose: out[n*K+k] = (f16) in[k*N+n] --------
__global__ __launch_bounds__(256) void wcvt_t(const float* __restrict__ in,
                                              f16* __restrict__ out, int K, int N) {
  __shared__ float tile[32][33];
  int n0 = blockIdx.x * 32, k0 = blockIdx.y * 32;
  int tx = threadIdx.x, ty = threadIdx.y;  // (32,8)
#pragma unroll
  for (int i = 0; i < 4; i++) {
    int k = k0 + ty + i * 8;
    tile[ty + i * 8][tx] = in[(size_t)k * N + n0 + tx];
  }
  __syncthreads();
#pragma unroll
  for (int i = 0; i < 4; i++) {
    int n = n0 + ty + i * 8;
    out[(size_t)n * K + k0 + tx] = (f16)tile[tx][ty + i * 8];
  }
}

// -------- LayerNorm fp32 in -> f16 out (+ optional f16 copy of input) -----
__global__ __launch_bounds__(256) void ln_k(const float* __restrict__ x,
                                            const float* __restrict__ w,
                                            const float* __restrict__ b,
                                            f16* __restrict__ out,
                                            f16* __restrict__ xcopy) {
  int row = blockIdx.x;
  int t = threadIdx.x;
  const float4* xr = (const float4*)(x + (size_t)row * HDIM);
  float4 v = xr[t];
  float s  = v.x + v.y + v.z + v.w;
  float s2 = v.x * v.x + v.y * v.y + v.z * v.z + v.w * v.w;
#pragma unroll
  for (int off = 32; off > 0; off >>= 1) {
    s  += __shfl_down(s, off);
    s2 += __shfl_down(s2, off);
  }
  __shared__ float red[8];
  int wid = t >> 6, lane = t & 63;
  if (lane == 0) { red[wid] = s; red[4 + wid] = s2; }
  __syncthreads();
  if (t == 0) {
    red[0] = red[0] + red[1] + red[2] + red[3];
    red[4] = red[4] + red[5] + red[6] + red[7];
  }
  __syncthreads();
  float mean = red[0] * (1.0f / HDIM);
  float var  = red[4] * (1.0f / HDIM) - mean * mean;
  float rstd = rsqrtf(var + 1e-5f);
  float4 ww = ((const float4*)w)[t];
  float4 bb = ((const float4*)b)[t];
  f16x4 o;
  o[0] = (f16)((v.x - mean) * rstd * ww.x + bb.x);
  o[1] = (f16)((v.y - mean) * rstd * ww.y + bb.y);
  o[2] = (f16)((v.z - mean) * rstd * ww.z + bb.z);
  o[3] = (f16)((v.w - mean) * rstd * ww.w + bb.w);
  ((f16x4*)(out + (size_t)row * HDIM))[t] = o;
  if (xcopy) {
    f16x4 c;
    c[0] = (f16)v.x; c[1] = (f16)v.y; c[2] = (f16)v.z; c[3] = (f16)v.w;
    ((f16x4*)(xcopy + (size_t)row * HDIM))[t] = c;
  }
}

// -------- LayerNorm f16 in -> f16 out, 128 thr/row, f16x8 loads --------
__global__ __launch_bounds__(128) void ln_k16(const f16* __restrict__ x,
                                              const float* __restrict__ w,
                                              const float* __restrict__ b,
                                              f16* __restrict__ out) {
  int row = blockIdx.x;
  int t = threadIdx.x;  // 0..127
  f16x8 xv = ((const f16x8*)(x + (size_t)row * HDIM))[t];
  float v[8];
  float s = 0.f, s2 = 0.f;
#pragma unroll
  for (int i = 0; i < 8; i++) {
    v[i] = (float)xv[i];
    s += v[i]; s2 += v[i] * v[i];
  }
#pragma unroll
  for (int off = 32; off > 0; off >>= 1) {
    s  += __shfl_down(s, off);
    s2 += __shfl_down(s2, off);
  }
  __shared__ float red[4];
  int wid = t >> 6, lane = t & 63;
  if (lane == 0) { red[wid] = s; red[2 + wid] = s2; }
  __syncthreads();
  float mean = (red[0] + red[1]) * (1.0f / HDIM);
  float var  = (red[2] + red[3]) * (1.0f / HDIM) - mean * mean;
  float rstd = rsqrtf(var + 1e-5f);
  float4 w1 = ((const float4*)w)[2 * t], w2 = ((const float4*)w)[2 * t + 1];
  float4 b1 = ((const float4*)b)[2 * t], b2 = ((const float4*)b)[2 * t + 1];
  float wv[8] = {w1.x, w1.y, w1.z, w1.w, w2.x, w2.y, w2.z, w2.w};
  float bv[8] = {b1.x, b1.y, b1.z, b1.w, b2.x, b2.y, b2.z, b2.w};
  f16x8 o;
#pragma unroll
  for (int i = 0; i < 8; i++) o[i] = (f16)((v[i] - mean) * rstd * wv[i] + bv[i]);
  ((f16x8*)(out + (size_t)row * HDIM))[t] = o;
}

// -------- GEMM: C[M,N] = act(A[M,K] @ BT[N,K]^T + bias) (+f16 resid) --------
// R17 = resubmit of R16 (container failed twice; kernel never ran — same
// infra signature as Round 3, whose resubmit then passed).
// R16 = R15 (verified 578.4us) with BARRIER REDUCTION: 4 -> 2 s_barrier per
// K-iter. Audit: only the ITER-TOP barrier is correctness-critical (makes
// the counted vmcnt collective + WAR-protects buffers being re-staged).
// The two post-stage-issue barriers protected nothing (DMA writes target
// buffers not read this iter); kept post-MFMA0 barrier for loose phase
// alignment. Deadlock audit: barrier count uniform (2/iter, no barriers
// under divergent guards). WAR audit: a wave reaches iter t+1's barrier-1
// only after its iter-t lgkmcnt(0)s retired all its ds_reads; re-staging
// of those buffers is issued only after that barrier.
// Pipeline (unchanged from R15): A 3-buf dist-2, B 2-buf dist-1-early,
// iter-top vmcnt(2); swizzle; setprio; vector epilogue.
// MODE: 0=none 2=silu 3=ug-split. XCD-banded 1-D grid swizzle.
template <int MODE, int RESID, int OUTF16>
__global__ __launch_bounds__(512, 2) void gemm256(const f16* __restrict__ A,
                                                  const f16* __restrict__ BT,
                                                  const float* __restrict__ bias,
                                                  const float* __restrict__ bias2,
                                                  const f16* __restrict__ resid,
                                                  void* __restrict__ Cout,
                                                  void* __restrict__ Cout2,
                                                  int M, int N, int K) {
  __shared__ __align__(16) f16 As[3][256 * 32];   // 3 x 16KB
  __shared__ __align__(16) f16 Bs[2][256 * 32];   // 2 x 16KB
  const int tid  = threadIdx.x;
  const int lane = tid & 63;
  const int wid  = tid >> 6;                 // 8 waves
  const int wm = wid >> 2, wn = wid & 3;     // 2 x 4 wave grid
  const int quad = lane >> 4, l16 = lane & 15;
  const int xq = (quad ^ ((l16 >> 1) & 3)) << 4;   // swizzled 16B slot (bytes)

  // XCD-banded swizzle over 256x256 tiles
  const int nbx = N >> 8, nby = M >> 8;
  const int b = blockIdx.x;
  const int xcd = b & 7;
  const int i = b >> 3;
  const int strips = nby >> 3;               // row strips per XCD
  const int rs = i / nbx, cb = i - rs * nbx;
  const long m0 = (long)(xcd * strips + rs) << 8;
  const long n0 = (long)cb << 8;

  // staging: unit = 128 rows x 32 k = 8KB = 512 thr x 16B (1 load each).
  // dest row = tid>>2, phys slot = tid&3; logical source slot pre-swizzled:
  // qs = (tid&3) ^ ((row>>1)&3) = (tid&3) ^ ((tid>>3)&3)   (rule #21)
  const int srow = tid >> 2;
  const int qs = (tid & 3) ^ ((tid >> 3) & 3);
  const f16* gA = A  + (size_t)(m0 + srow) * K + qs * 8;
  const f16* gB = BT + (size_t)(n0 + srow) * K + qs * 8;
  const int sdst = tid * 16;                 // byte offset within an 8KB unit

  f32x4 zero = {0.f, 0.f, 0.f, 0.f};
  f32x4 acc[8][4];
#pragma unroll
  for (int mi = 0; mi < 8; ++mi)
#pragma unroll
    for (int ni = 0; ni < 4; ++ni) acc[mi][ni] = zero;

  // prologue: A(0), B(0), A(1)  (order matters for the uniform vmcnt(2))
#pragma unroll
  for (int h = 0; h < 2; ++h)
    __builtin_amdgcn_global_load_lds(AS1(gA + (size_t)h * 128 * K),
                                     AS3((char*)As[0] + h * 8192 + sdst), 16, 0, 0);
#pragma unroll
  for (int h = 0; h < 2; ++h)
    __builtin_amdgcn_global_load_lds(AS1(gB + (size_t)h * 128 * K),
                                     AS3((char*)Bs[0] + h * 8192 + sdst), 16, 0, 0);
#pragma unroll
  for (int h = 0; h < 2; ++h)
    __builtin_amdgcn_global_load_lds(AS1(gA + (size_t)h * 128 * K + 32),
                                     AS3((char*)As[1] + h * 8192 + sdst), 16, 0, 0);

  const int nt = K >> 5;
  int cur = 0;                               // t % 3 (A buffer index)
  for (int t = 0; t < nt; ++t) {
    // counted wait: newest needed op is B(t); only A(t+1)'s 2 loads newer.
    if (t < nt - 1) asm volatile("s_waitcnt vmcnt(2)" ::: "memory");
    else            asm volatile("s_waitcnt vmcnt(0)" ::: "memory");
    __builtin_amdgcn_sched_barrier(0);
    __builtin_amdgcn_s_barrier();            // BARRIER 1 (correctness)
    const f16* Ab = As[cur];
    const f16* Bb = Bs[t & 1];
    const int stgA = (cur + 2 >= 3) ? cur - 1 : cur + 2;   // (t+2)%3

    // ---- phase 0: A-frags mi 0-3 + all B-frags; stage B of t+1 (early) ----
    f16x8 af[4], bf[4];
#pragma unroll
    for (int mi = 0; mi < 4; ++mi) {
      const int row = wm * 128 + mi * 16 + l16;
      af[mi] = *(const f16x8*)((const char*)Ab + row * 64 + xq);
    }
#pragma unroll
    for (int ni = 0; ni < 4; ++ni) {
      const int row = wn * 64 + ni * 16 + l16;
      bf[ni] = *(const f16x8*)((const char*)Bb + row * 64 + xq);
    }
    if (t + 1 < nt) {
      const size_t koff = (size_t)(t + 1) * 32;
#pragma unroll
      for (int h = 0; h < 2; ++h)
        __builtin_amdgcn_global_load_lds(AS1(gB + (size_t)h * 128 * K + koff),
                                         AS3((char*)Bs[(t + 1) & 1] + h * 8192 + sdst), 16, 0, 0);
    }
    // (no barrier here — DMA targets a buffer not read this iter)
    asm volatile("s_waitcnt lgkmcnt(0)" ::: "memory");
    __builtin_amdgcn_sched_barrier(0);
    __builtin_amdgcn_s_setprio(1);
#pragma unroll
    for (int mi = 0; mi < 4; ++mi)
#pragma unroll
      for (int ni = 0; ni < 4; ++ni)
        acc[mi][ni] = __builtin_amdgcn_mfma_f32_16x16x32_f16(bf[ni], af[mi], acc[mi][ni], 0, 0, 0);
    __builtin_amdgcn_s_setprio(0);
    __builtin_amdgcn_sched_barrier(0);
    __builtin_amdgcn_s_barrier();            // BARRIER 2 (phase alignment)

    // ---- phase 1: A-frags mi 4-7 (B held in regs); stage A of t+2 ----
    f16x8 af2[4];
#pragma unroll
    for (int mi = 0; mi < 4; ++mi) {
      const int row = wm * 128 + (4 + mi) * 16 + l16;
      af2[mi] = *(const f16x8*)((const char*)Ab + row * 64 + xq);
    }
    if (t + 2 < nt) {
      const size_t koff = (size_t)(t + 2) * 32;
#pragma unroll
      for (int h = 0; h < 2; ++h)
        __builtin_amdgcn_global_load_lds(AS1(gA + (size_t)h * 128 * K + koff),
                                         AS3((char*)As[stgA] + h * 8192 + sdst), 16, 0, 0);
    }
    // (no barrier here either)
    asm volatile("s_waitcnt lgkmcnt(0)" ::: "memory");
    __builtin_amdgcn_sched_barrier(0);
    __builtin_amdgcn_s_setprio(1);
#pragma unroll
    for (int mi = 0; mi < 4; ++mi)
#pragma unroll
      for (int ni = 0; ni < 4; ++ni)
        acc[4 + mi][ni] = __builtin_amdgcn_mfma_f32_16x16x32_f16(bf[ni], af2[mi], acc[4 + mi][ni], 0, 0, 0);
    __builtin_amdgcn_s_setprio(0);
    __builtin_amdgcn_sched_barrier(0);
    // no trailing barrier: next iter-top vmcnt+barrier covers WAR/RAW
    cur = (cur == 2) ? 0 : cur + 1;
  }

  // epilogue (R11-verified transposed mapping): row fixed per (mi,l16),
  // 4 consecutive cols per (ni,quad) -> vector stores.
#pragma unroll
  for (int mi = 0; mi < 8; ++mi) {
    const long row = m0 + wm * 128 + mi * 16 + l16;
#pragma unroll
    for (int ni = 0; ni < 4; ++ni) {
      const long col = n0 + wn * 64 + ni * 16 + quad * 4;   // %4 == 0
      const float* bp;
      if (MODE == 3) bp = (col < HDIM) ? (bias + col) : (bias2 + (col - HDIM));
      else           bp = bias + col;
      f32x4 v = acc[mi][ni] + *(const f32x4*)bp;
      if (MODE == 2) {
#pragma unroll
        for (int r = 0; r < 4; ++r) v[r] = v[r] / (1.f + __expf(-v[r]));
      }
      if (MODE == 3) {
        if (col < HDIM) {
          f16x4 o;
#pragma unroll
          for (int r = 0; r < 4; ++r) o[r] = (f16)v[r];
          *(f16x4*)((f16*)Cout + row * HDIM + col) = o;
        } else {
          f16x4 o;
#pragma unroll
          for (int r = 0; r < 4; ++r) o[r] = (f16)(1.f / (1.f + __expf(-v[r])));
          *(f16x4*)((f16*)Cout2 + row * HDIM + (col - HDIM)) = o;
        }
      } else {
        if (RESID) {
          f16x4 rv = *(const f16x4*)(resid + row * N + col);
#pragma unroll
          for (int r = 0; r < 4; ++r) v[r] += (float)rv[r];
        }
        if (OUTF16) {
          f16x4 o;
#pragma unroll
          for (int r = 0; r < 4; ++r) o[r] = (f16)v[r];
          *(f16x4*)((f16*)Cout + row * N + col) = o;
        } else {
          *(f32x4*)((float*)Cout + row * N + col) = v;
        }
      }
    }
  }
}

// -------- scan pass 1: per-chunk local fwd & bwd carries (one read pass) ----
__global__ __launch_bounds__(256) void scan_p1(const f16* __restrict__ u,
                                               const float* __restrict__ sdecay,
                                               float* __restrict__ carry_f,
                                               float* __restrict__ carry_b) {
  int tid = blockIdx.x * 256 + threadIdx.x;
  int h = tid & (HDIM - 1);
  int c = tid >> 10;
  float d = 1.f / (1.f + expf(-sdecay[h]));
  const f16* up = u + (size_t)c * CH * HDIM + h;
  float sf = 0.f, sb = 0.f, p = 1.f;
#pragma unroll
  for (int i = 0; i < CH; i++) {
    float uu = (float)up[i * HDIM];
    sf = d * sf + uu;   // local fwd final
    sb += p * uu;       // local bwd final = sum d^i * u_i
    p *= d;
  }
  carry_f[(size_t)c * HDIM + h] = sf;
  carry_b[(size_t)c * HDIM + h] = sb;
}

// -------- scan pass 2: chunk-level exclusive scans (fwd dir=0, bwd dir=1) --
__global__ __launch_bounds__(256) void scan_p2(const float* __restrict__ sdecay,
                                               const float* __restrict__ carry_f,
                                               const float* __restrict__ carry_b,
                                               float* __restrict__ cin_f,
                                               float* __restrict__ cin_b) {
  int tid = blockIdx.x * 256 + threadIdx.x;  // 2048 threads
  int h = tid & (HDIM - 1);
  int dir = tid >> 10;
  float d = 1.f / (1.f + expf(-sdecay[h]));
  float dT = powf(d, (float)CH);
  float S = 0.f;
  if (dir == 0) {
#pragma unroll 4
    for (int c = 0; c < NC; c++) {
      cin_f[(size_t)c * HDIM + h] = S;
      S = dT * S + carry_f[(size_t)c * HDIM + h];
    }
  } else {
#pragma unroll 4
    for (int c = NC - 1; c >= 0; c--) {
      cin_b[(size_t)c * HDIM + h] = S;
      S = dT * S + carry_b[(size_t)c * HDIM + h];
    }
  }
}

// -------- scan pass 3: re-scan chunk with carries, fuse gate, f16 out ------
__global__ __launch_bounds__(256) void scan_p3(const f16* __restrict__ u,
                                               const f16* __restrict__ gate,
                                               const float* __restrict__ sdecay,
                                               const float* __restrict__ cin_f,
                                               const float* __restrict__ cin_b,
                                               f16* __restrict__ state_out) {
  int tid = blockIdx.x * 256 + threadIdx.x;
  int h = tid & (HDIM - 1);
  int c = tid >> 10;
  float d = 1.f / (1.f + expf(-sdecay[h]));
  const f16* up = u    + (size_t)c * CH * HDIM + h;
  const f16* gp = gate + (size_t)c * CH * HDIM + h;
  f16* op = state_out  + (size_t)c * CH * HDIM + h;
  float ur[CH], sf[CH];
#pragma unroll
  for (int i = 0; i < CH; i++) ur[i] = (float)up[i * HDIM];
  float s = cin_f[(size_t)c * HDIM + h];
#pragma unroll
  for (int i = 0; i < CH; i++) { s = d * s + ur[i]; sf[i] = s; }
  s = cin_b[(size_t)c * HDIM + h];
#pragma unroll
  for (int i = CH - 1; i >= 0; i--) {
    s = d * s + ur[i];
    float g = (float)gp[i * HDIM];
    op[i * HDIM] = (f16)(0.5f * (sf[i] + s) * g);
  }
}

extern "C" void kernel_launch(void* const* d_in, const int* in_sizes, int n_in,
                              void* d_out, int out_size, void* d_ws, size_t ws_size,
                              hipStream_t stream) {
  const float* x      = (const float*)d_in[0];
  const float* ln1_w  = (const float*)d_in[1];
  const float* ln1_b  = (const float*)d_in[2];
  const float* W_in   = (const float*)d_in[3];
  const float* b_in   = (const float*)d_in[4];
  const float* W_gate = (const float*)d_in[5];
  const float* b_gate = (const float*)d_in[6];
  const float* W_out  = (const float*)d_in[7];
  const float* b_out  = (const float*)d_in[8];
  const float* sdecay = (const float*)d_in[9];
  const float* ln2_w  = (const float*)d_in[10];
  const float* ln2_b  = (const float*)d_in[11];
  const float* W_ff1  = (const float*)d_in[12];
  const float* b_ff1  = (const float*)d_in[13];
  const float* W_ff2  = (const float*)d_in[14];
  const float* b_ff2  = (const float*)d_in[15];
  float* out = (float*)d_out;

  char* ws = (char*)d_ws;
  const size_t MB32 = 33554432, MB64 = 67108864;
  f16* hidden = (f16*)(ws);                 // 32MB; reused as state_out
  f16* xh     = (f16*)(ws + MB32);          // 32MB f16 copy of x
  f16* u      = (f16*)(ws + 2 * MB32);      // 32MB; reused as h2
  f16* gate   = (f16*)(ws + 3 * MB32);      // 32MB
  f16* x2h    = (f16*)(ws + 4 * MB32);      // 32MB f16 x2
  f16* ff     = (f16*)(ws + 5 * MB32);      // 64MB
  char* wbase = ws + 5 * MB32 + MB64;
  f16* wt_ug  = (f16*)(wbase);                       // 4MB (2048x1024)
  f16* wt_out = (f16*)(wbase + 4194304);             // 2MB
  f16* wt_ff1 = (f16*)(wbase + 4194304 + 2097152);   // 4MB
  f16* wt_ff2 = (f16*)(wbase + 2 * 4194304 + 2097152); // 4MB
  char* cbase = wbase + 3 * 4194304 + 2097152;
  float* carry_f = (float*)(cbase);
  float* carry_b = (float*)(cbase + 2097152);
  float* cin_f   = (float*)(cbase + 2 * 2097152);
  float* cin_b   = (float*)(cbase + 3 * 2097152);
  f16* state_out = hidden;  // hidden dead after fused u/gate GEMM
  f16* h2        = u;       // u dead after scan_p3

  dim3 tb(32, 8);
  wcvt_t<<<dim3(32, 32), tb, 0, stream>>>(W_in,   wt_ug,                 1024, 1024);
  wcvt_t<<<dim3(32, 32), tb, 0, stream>>>(W_gate, wt_ug + 1024 * 1024,   1024, 1024);
  wcvt_t<<<dim3(32, 32), tb, 0, stream>>>(W_out,  wt_out,                1024, 1024);
  wcvt_t<<<dim3(64, 32), tb, 0, stream>>>(W_ff1,  wt_ff1,                1024, 2048);
  wcvt_t<<<dim3(32, 64), tb, 0, stream>>>(W_ff2,  wt_ff2,                2048, 1024);

  ln_k<<<L_SEQ, 256, 0, stream>>>(x, ln1_w, ln1_b, hidden, xh);

  // fused u + gate: N=2048  (64x8 = 512 tiles of 256x256)
  gemm256<3, 0, 1><<<512, 512, 0, stream>>>(hidden, wt_ug, b_in, b_gate, nullptr,
                                            u, gate, L_SEQ, 2048, 1024);

  scan_p1<<<2048, 256, 0, stream>>>(u, sdecay, carry_f, carry_b);
  scan_p2<<<8, 256, 0, stream>>>(sdecay, carry_f, carry_b, cin_f, cin_b);
  scan_p3<<<2048, 256, 0, stream>>>(u, gate, sdecay, cin_f, cin_b, state_out);

  // x2 = x + state_out @ W_out + b_out  (f16 out)  (64x4 = 256 tiles)
  gemm256<0, 1, 1><<<256, 512, 0, stream>>>(state_out, wt_out, b_out, nullptr, xh,
                                            x2h, nullptr, L_SEQ, 1024, 1024);

  ln_k16<<<L_SEQ, 128, 0, stream>>>(x2h, ln2_w, ln2_b, h2);

  gemm256<2, 0, 1><<<512, 512, 0, stream>>>(h2, wt_ff1, b_ff1, nullptr, nullptr,
                                            ff, nullptr, L_SEQ, 2048, 1024);

  // out = x2 + silu(h2@W_ff1) @ W_ff2 + b_ff2  (fp32 out)  (64x4 = 256 tiles)
  gemm256<0, 1, 0><<<256, 512, 0, stream>>>(ff, wt_ff2, b_ff2, nullptr, x2h,
                                            out, nullptr, L_SEQ, 1024, 2048);
}